// Round 3
// baseline (158.830 us; speedup 1.0000x reference)
//
#include <hip/hip_runtime.h>

#define CH   128
#define KS   7
#define R    49
#define HH   56
#define NPOS 3136
#define BS   8
#define XSTR 401408
#define XTOT (BS*XSTR)

typedef short short8 __attribute__((ext_vector_type(8)));
typedef float f32x4  __attribute__((ext_vector_type(4)));

__device__ __forceinline__ short f2bf(float f) {            // RNE fp32->bf16
    unsigned u = __float_as_uint(f);
    u += 0x7fffu + ((u >> 16) & 1u);
    return (short)(u >> 16);
}
__device__ __forceinline__ float bf2f(short s) {
    return __uint_as_float(((unsigned)(unsigned short)s) << 16);
}

#define HSTR 136            // hid LDS row stride (bf16 elems): pad breaks b128 conflicts
#define PSTR 132            // P LDS row stride (fp32): 2-way (free) bank pattern

// prep: W2 (128x128 fp32, [m][ch]) -> W2^T hi/lo bf16 ([ch][m]) in ws
__global__ __launch_bounds__(256) void poatt_prep(
    const float* __restrict__ W2, short* __restrict__ wsH, short* __restrict__ wsL)
{
    int t = blockIdx.x * 256 + threadIdx.x;   // 64 blocks * 256 = 16384
    int k = t >> 7, ch = t & 127;
    float w = W2[k * CH + ch];
    short hi = f2bf(w);
    wsH[ch * CH + k] = hi;
    wsL[ch * CH + k] = f2bf(w - bf2f(hi));
}

template<bool WS_W2, bool USE_WS>
__global__ __launch_bounds__(256, 4) void poatt_main(
    const float* __restrict__ x,
    const float* __restrict__ W1, const float* __restrict__ b1,
    const float* __restrict__ W2,
    const short* __restrict__ wsH, const short* __restrict__ wsL,
    float* __restrict__ dst)    // USE_WS: (b,pos,ch) ; else (b,ch,pos)
{
    __shared__ float rel_s[R][2];
    __shared__ __align__(16) char smem[2 * 64 * HSTR * 2];   // 34816 B
    short* hidH = (short*)smem;
    short* hidL = hidH + 64 * HSTR;
    float* Pbuf = (float*)smem;                 // overlay after MFMA: [49][PSTR]

    const int pos = blockIdx.x;
    const int tid = threadIdx.x;
    const int ch  = tid & (CH - 1);
    const int g   = tid >> 7;

    const int q  = pos >> 6;
    const int ii = q / KS;
    const int jj = q % KS;

    // ---------- phase 0: rel ----------
    if (tid < 2 * R) {
        const int e  = (tid >= R) ? 1 : 0;
        const int rr = tid - e * R;
        int F  = (pos * 2 + e) * R + rr;
        int ep = F & 1;
        int t  = F >> 1;
        int jp = t % HH; t /= HH;
        int a  = t % HH; t /= HH;
        int jc = t % KS;
        int ic = t / KS;
        int row = jp + ic - 3;
        int col = ep + jc - 3;
        float v = 0.0f;
        if (row >= 0 && row < HH && (col == 0 || col == 1)) {
            int f    = a * (HH * 2) + row * 2 + col;
            int cidx = f / NPOS;
            int p    = f - cidx * NPOS;
            int u    = (cidx == 0) ? (p / HH) : (p % HH);
            v = -3.0f + 6.0f * (float)u * (1.0f / 55.0f);
        }
        const float c0 = -3.0f + 6.0f * (float)(pos / HH) * (1.0f / 55.0f);
        const float c1 = -3.0f + 6.0f * (float)(pos % HH) * (1.0f / 55.0f);
        rel_s[rr][e] = v - ((e == 0) ? c0 : c1);
    }
    __syncthreads();

    // ---------- phase 1: hid = relu(rel@W1+b1) -> bf16 hi/lo in LDS ----------
    {
        const float w10 = W1[ch];
        const float w11 = W1[CH + ch];
        const float bb  = b1[ch];
        for (int rr = g; rr < R; rr += 2) {
            float h = fmaf(rel_s[rr][0], w10, fmaf(rel_s[rr][1], w11, bb));
            h = fmaxf(h, 0.0f);
            short hi = f2bf(h);
            hidH[rr * HSTR + ch] = hi;
            hidL[rr * HSTR + ch] = f2bf(h - bf2f(hi));
        }
        for (int t = tid; t < 15 * HSTR; t += 256) {   // zero pad rows 49..63
            hidH[R * HSTR + t] = 0;
            hidL[R * HSTR + t] = 0;
        }
    }
    __syncthreads();

    // ---------- phase 2: P = hid @ W2 via 3-term bf16 MFMA ----------
    {
        const int w  = tid >> 6;       // wave id = M-tile
        const int l  = tid & 63;
        const int lr = l & 15;
        const int kg = l >> 4;

        short8 aH[4], aL[4];
        const int abase = (16 * w + lr) * HSTR + kg * 8;
        #pragma unroll
        for (int kk = 0; kk < 4; ++kk) {
            aH[kk] = *reinterpret_cast<const short8*>(&hidH[abase + kk * 32]);
            aL[kk] = *reinterpret_cast<const short8*>(&hidL[abase + kk * 32]);
        }

        f32x4 acc[8];
        #pragma unroll
        for (int n = 0; n < 8; ++n) acc[n] = (f32x4)0.0f;

        #pragma unroll
        for (int n = 0; n < 8; ++n) {
            const int bcol = 16 * n + lr;
            #pragma unroll
            for (int kk = 0; kk < 4; ++kk) {
                short8 bH, bL;
                if (WS_W2) {
                    bH = *reinterpret_cast<const short8*>(wsH + bcol * CH + kk * 32 + kg * 8);
                    bL = *reinterpret_cast<const short8*>(wsL + bcol * CH + kk * 32 + kg * 8);
                } else {
                    #pragma unroll
                    for (int j = 0; j < 8; ++j) {
                        float ww = W2[(kk * 32 + kg * 8 + j) * CH + bcol];
                        short hi = f2bf(ww);
                        bH[j] = hi;
                        bL[j] = f2bf(ww - bf2f(hi));
                    }
                }
                acc[n] = __builtin_amdgcn_mfma_f32_16x16x32_bf16(aL[kk], bH, acc[n], 0, 0, 0);
                acc[n] = __builtin_amdgcn_mfma_f32_16x16x32_bf16(aH[kk], bL, acc[n], 0, 0, 0);
                acc[n] = __builtin_amdgcn_mfma_f32_16x16x32_bf16(aH[kk], bH, acc[n], 0, 0, 0);
            }
        }
        __syncthreads();               // hid reads done before overlay write

        #pragma unroll
        for (int n = 0; n < 8; ++n) {
            #pragma unroll
            for (int r = 0; r < 4; ++r) {
                int rr = 16 * w + kg * 4 + r;     // C/D: col=lane&15, row=(lane>>4)*4+reg
                if (rr < R) Pbuf[rr * PSTR + 16 * n + lr] = acc[n][r];
            }
        }
    }
    __syncthreads();

    // ---------- phase 3: softmax over rr + validity mask (b2 cancels) ----------
    if (tid < CH) {
        float p[R];
        #pragma unroll
        for (int rr = 0; rr < R; ++rr) p[rr] = Pbuf[rr * PSTR + tid];
        float mx = p[0];
        #pragma unroll
        for (int rr = 1; rr < R; ++rr) mx = fmaxf(mx, p[rr]);
        float s = 0.0f;
        #pragma unroll
        for (int rr = 0; rr < R; ++rr) { p[rr] = __expf(p[rr] - mx); s += p[rr]; }
        const float inv = 1.0f / s;
        const int wb0 = (pos & 63) * (R * CH);
        #pragma unroll
        for (int rr = 0; rr < R; ++rr) {
            int rem = wb0 + tid * R + rr;
            int e2  = rem & (CH - 1);
            int j2  = (rem >> 7) % HH;
            int row = j2 + ii - 3;
            int col = e2 + jj - 3;
            bool valid = (row >= 0) && (row < HH) && (col >= 0) && (col < CH);
            Pbuf[rr * PSTR + tid] = valid ? p[rr] * inv : 0.0f;
        }
    }
    __syncthreads();

    // ---------- phase 4: direct-global gather, 4 batches per thread ----------
    float p[R];
    #pragma unroll
    for (int rr = 0; rr < R; ++rr) p[rr] = Pbuf[rr * PSTR + ch];

    const int winbase = (pos & 63) * (R * CH) + (ii - 3) * CH + (jj - 3);
    const int base_t  = winbase + ch * R;

    #pragma unroll
    for (int bi = 0; bi < 4; ++bi) {
        const int b  = g * 4 + bi;
        const int ab = b * XSTR + base_t;
        const bool safe = (b > 0 || winbase >= 0) && (b < BS - 1 || winbase + R * CH <= XSTR);
        float acc = 0.0f;
        if (safe) {
            #pragma unroll
            for (int rr = 0; rr < R; ++rr) acc = fmaf(p[rr], x[ab + rr], acc);
        } else {
            #pragma unroll
            for (int rr = 0; rr < R; ++rr) {
                int a2 = ab + rr;
                a2 = a2 < 0 ? 0 : (a2 >= XTOT ? XTOT - 1 : a2);
                acc = fmaf(p[rr], x[a2], acc);
            }
        }
        if (USE_WS) dst[((size_t)b * NPOS + pos) * CH + ch] = acc;
        else        dst[((size_t)b * CH + ch) * NPOS + pos] = acc;
    }
}

// transpose (b,pos,ch) -> (b,ch,pos)
__global__ __launch_bounds__(256) void poatt_tr(
    const float* __restrict__ ws, float* __restrict__ out)
{
    __shared__ float t[64 * 129];
    const int blk = blockIdx.x;
    const int b   = blk / 49;
    const int p0  = (blk % 49) * 64;
    const int tid = threadIdx.x;

    const int chR = tid & 127, pR = tid >> 7;
    #pragma unroll
    for (int r = 0; r < 32; ++r) {
        int pl = pR + 2 * r;
        t[pl * 129 + chR] = ws[((size_t)b * NPOS + p0 + pl) * CH + chR];
    }
    __syncthreads();
    const int pW = tid & 63, chW0 = tid >> 6;
    #pragma unroll
    for (int c = 0; c < 32; ++c) {
        int chl = chW0 + 4 * c;
        out[((size_t)b * CH + chl) * NPOS + p0 + pW] = t[pW * 129 + chl];
    }
}

extern "C" void kernel_launch(void* const* d_in, const int* in_sizes, int n_in,
                              void* d_out, int out_size, void* d_ws, size_t ws_size,
                              hipStream_t stream) {
    (void)in_sizes; (void)n_in; (void)out_size;
    const float* x  = (const float*)d_in[0];
    const float* W1 = (const float*)d_in[1];
    const float* b1 = (const float*)d_in[2];
    const float* W2 = (const float*)d_in[3];
    float* out = (float*)d_out;

    const size_t W2T_BYTES = 2u * CH * CH * sizeof(short);          // 65536
    const size_t TR_BYTES  = (size_t)BS * NPOS * CH * sizeof(float);

    short* wsH = (short*)d_ws;
    short* wsL = wsH + CH * CH;

    if (ws_size >= W2T_BYTES) {
        poatt_prep<<<dim3(64), dim3(256), 0, stream>>>(W2, wsH, wsL);
    }
    if (ws_size >= W2T_BYTES + TR_BYTES) {
        float* trb = (float*)((char*)d_ws + W2T_BYTES);
        poatt_main<true, true><<<dim3(NPOS), dim3(256), 0, stream>>>(
            x, W1, b1, W2, wsH, wsL, trb);
        poatt_tr<<<dim3(BS * 49), dim3(256), 0, stream>>>(trb, out);
    } else if (ws_size >= W2T_BYTES) {
        poatt_main<true, false><<<dim3(NPOS), dim3(256), 0, stream>>>(
            x, W1, b1, W2, wsH, wsL, out);
    } else {
        poatt_main<false, false><<<dim3(NPOS), dim3(256), 0, stream>>>(
            x, W1, b1, W2, nullptr, nullptr, out);
    }
}